// Round 8
// baseline (4612.418 us; speedup 1.0000x reference)
//
#include <hip/hip_runtime.h>
#include <stdint.h>

#define BATCH   4
#define NPTS    16384
#define NPOINT  1024
#define KNN     20
#define KSEL    21   // K+1, includes self

typedef unsigned long long u64;

// ---------------------------------------------------------------------------
// r26: 2-way partitioned FPS, fully LDS-resident, minimal-contention
// exchange.
// Post-mortem r25: 4-way split was exchange-bound (~2.8us/iter): ALL 512
// threads polled ALL 4 slots with un-coalescable agent atomics (2048
// atomic loads/round) across 4 different XCDs. The protocol itself was
// validated bit-exact (absmax 0.0).
// Design:
//  - FPSB=2 blocks/batch; each block's 8192-pt partition lives ENTIRELY
//    in LDS: xy-pairs 64KB + z-pairs 32KB (r23 packing, 0 bank conflicts
//    measured) + md[16][512] 32KB ([i][t], 2-way=free) = 128KB. Zero
//    persistent register state (kills r19-r21 spill), zero per-iter
//    global streaming (kills r22/r24 latency).
//  - Exchange: only lanes 0-1 of wave 0 poll (1 slot each), __shfl
//    combine, winner broadcast via LDS + existing barrier. Tagged-key
//    protocol from r25: key=(fbits<<32)|((16383-idx)<<10)|it; bit63=0
//    valid, 0xAA poison/zeroed ws invalid, replay idempotent (tag must
//    match exactly; slot overwritten long before tag could recur).
//    Tie-break == reference argmax (max dist, then lowest index).
//  - XCD heuristic: 16-block grid, batch b -> blockIdx {b, b+8}; if
//    placement is round-robin mod 8 both land on XCD b -> exchange stays
//    in one L2. Perf-only bet, correctness-independent.
// FP trees / scan order (local stride ascending, idx=blkoff+i*512+t) /
// reduce / tie-break byte-identical to validated r19/r25.
// knn_kernel unchanged from validated r19.
// ---------------------------------------------------------------------------
#define FPSB   2                          // FPS blocks per batch
#define FPST   512                        // threads per FPS block
#define BLKPTS (NPTS / FPSB)              // 8192 points per block
#define NSTR   (BLKPTS / FPST)            // 16 strides (pts per thread)
#define LPAIRS (NSTR / 2)                 // 8 coord pairs
#define DYN_LDS_BYTES ((LPAIRS * FPST * 6 + BLKPTS) * 4)   // 131072 B
#define KNNT   512

// ===========================================================================
// Dispatch 1: FPS. Grid = 16 blocks; batch b on blockIdx {b, b+8}.
// ===========================================================================
__global__ __launch_bounds__(FPST)
void fps_kernel(const float* __restrict__ pts, float* __restrict__ out,
                int* __restrict__ slots, u64* __restrict__ cand) {
  const int gb = blockIdx.x;
  const int b  = gb & 7;                  // batch (if < BATCH)
  const int j  = gb >> 3;                 // sub-block 0/1
  if (b >= BATCH) return;                 // blocks 4..7, 12..15 idle
  const int blkoff = j * BLKPTS;
  const float* P = pts + (size_t)b * NPTS * 3;
  float* out_ind = out;                   // [B,NPOINT] (indices as float)
  float* out_q   = out + BATCH * NPOINT;  // [B,NPOINT,3]
  const int t = threadIdx.x;

  extern __shared__ float lds[];
  float4* sxy2 = (float4*)lds;                        // 16384 floats (64KB)
  float2* sz2  = (float2*)(lds + LPAIRS * FPST * 4);  //  8192 floats (32KB)
  float*  mdl  = lds + LPAIRS * FPST * 6;             //  8192 floats (32KB)

  // One-time fill of this block's partition (r23-validated packing).
#pragma unroll
  for (int u = 0; u < LPAIRS; ++u) {
    int ia = blkoff + (2 * u) * FPST + t;
    int ib = ia + FPST;
    float4 c;
    c.x = P[ia * 3 + 0]; c.y = P[ia * 3 + 1];
    c.z = P[ib * 3 + 0]; c.w = P[ib * 3 + 1];
    sxy2[u * FPST + t] = c;
    float2 zz;
    zz.x = P[ia * 3 + 2]; zz.y = P[ib * 3 + 2];
    sz2[u * FPST + t] = zz;
  }
#pragma unroll
  for (int i = 0; i < NSTR; ++i) mdl[i * FPST + t] = 1e10f;

  __shared__ float s_val[2][FPST / 64];
  __shared__ int   s_idx[2][FPST / 64];
  __shared__ int   s_win[2];

  if (j == 0 && t == 0) {
    out_ind[b * NPOINT] = 0.0f;
    slots[b * NPOINT] = 0;
    float ax = P[0], ay = P[1], az = P[2];
    size_t o0 = (size_t)(b * NPOINT) * 3;
    out_q[o0 + 0] = ax; out_q[o0 + 1] = ay; out_q[o0 + 2] = az;
  }
  float qx = P[0], qy = P[1], qz = P[2];

  __syncthreads();   // LDS fill visible

  for (int it = 1; it < NPOINT; ++it) {
    const int p = it & 1;
    float best = -1.0f;
    int bi = 0;

    // Scan this block's 16 strides, ascending (bitwise-identical tree).
#pragma unroll
    for (int u = 0; u < LPAIRS; ++u) {
      float4 c  = sxy2[u * FPST + t];
      float2 zz = sz2[u * FPST + t];
      const int i0 = 2 * u, i1 = 2 * u + 1;
      {
        float m0 = mdl[i0 * FPST + t];
        float dx = __fsub_rn(c.x, qx);
        float dy = __fsub_rn(c.y, qy);
        float dz = __fsub_rn(zz.x, qz);
        float d  = __fadd_rn(__fadd_rn(__fmul_rn(dx, dx), __fmul_rn(dy, dy)),
                             __fmul_rn(dz, dz));
        float m = fminf(m0, d);
        mdl[i0 * FPST + t] = m;
        bool g = (m > best);
        best = g ? m : best;
        bi   = g ? i0 : bi;
      }
      {
        float m1 = mdl[i1 * FPST + t];
        float dx = __fsub_rn(c.z, qx);
        float dy = __fsub_rn(c.w, qy);
        float dz = __fsub_rn(zz.y, qz);
        float d  = __fadd_rn(__fadd_rn(__fmul_rn(dx, dx), __fmul_rn(dy, dy)),
                             __fmul_rn(dz, dz));
        float m = fminf(m1, d);
        mdl[i1 * FPST + t] = m;
        bool g = (m > best);
        best = g ? m : best;
        bi   = g ? i1 : bi;
      }
    }

    int bidx = blkoff + bi * FPST + t;    // global point index

    // wave argmax reduce, tie -> lower global index (validated)
#pragma unroll
    for (int off = 32; off >= 1; off >>= 1) {
      float ov = __shfl_down(best, off);
      int   oi = __shfl_down(bidx, off);
      if (ov > best || (ov == best && oi < bidx)) { best = ov; bidx = oi; }
    }

    if ((t & 63) == 0) { s_val[p][t >> 6] = best; s_idx[p][t >> 6] = bidx; }
    __syncthreads();

    float bv = s_val[p][0];
    int   bx = s_idx[p][0];
#pragma unroll
    for (int w = 1; w < FPST / 64; ++w) {
      float v = s_val[p][w];
      int   x = s_idx[p][w];
      if (v > bv || (v == bv && x < bx)) { bv = v; bx = x; }
    }

    // Publish this block's candidate (r25-validated key packing).
    if (t == 0) {
      u64 pv = ((u64)__float_as_uint(bv) << 32)
             | ((u64)(unsigned)(16383 - bx) << 10)
             | (unsigned)it;
      __hip_atomic_store(&cand[((size_t)b * 2 + p) * FPSB + j], pv,
                         __ATOMIC_RELAXED, __HIP_MEMORY_SCOPE_AGENT);
    }

    // Lanes 0-1 of wave 0 poll one slot each; shfl-combine; LDS broadcast.
    u64 v = 0;
    if (t < FPSB) {
      const u64* sp = &cand[((size_t)b * 2 + p) * FPSB + t];
      for (;;) {
        v = __hip_atomic_load(sp, __ATOMIC_RELAXED,
                              __HIP_MEMORY_SCOPE_AGENT);
        if ((v >> 63) == 0 &&
            (unsigned)(v & 0x3FFu) == (unsigned)it) break;
        __builtin_amdgcn_s_sleep(1);
      }
    }
    if (t < 64) {
      u64 k0 = __shfl(v, 0);
      u64 k1 = __shfl(v, 1);
      u64 wkey = (k0 > k1) ? k0 : k1;
      if (t == 0) s_win[p] = 16383 - (int)((wkey >> 10) & 0x3FFFu);
    }
    __syncthreads();
    const int wx = s_win[p];

    qx = P[wx * 3 + 0];
    qy = P[wx * 3 + 1];
    qz = P[wx * 3 + 2];

    if (j == 0 && t == 0) {
      slots[b * NPOINT + it] = wx;
      out_ind[b * NPOINT + it] = (float)wx;
      size_t o = (size_t)(b * NPOINT + it) * 3;
      out_q[o + 0] = qx; out_q[o + 1] = qy; out_q[o + 2] = qz;
    }
  }
}

// ===========================================================================
// Dispatch 2: KNN consumers. Blocks 0..511 = knn_mid, 512..1023 = knn_out.
// One wave per query. Bodies unchanged from validated r19.
// ===========================================================================
__global__ __launch_bounds__(KNNT, 4)
void knn_kernel(const float* __restrict__ pts,
                const int* __restrict__ slots,
                float* __restrict__ out_nbr_mid,
                float* __restrict__ out_d_mid,
                float* __restrict__ out_nbr_out,
                float* __restrict__ out_d_out) {
  if (blockIdx.x < 512) {
    // ================= knn_mid role: one wave per query ===================
#pragma clang fp contract(off)
    const int kb   = blockIdx.x;
    const int wid  = kb * 8 + (threadIdx.x >> 6);
    const int lane = threadIdx.x & 63;
    const int b    = wid >> 10;
    const int qi   = wid & (NPOINT - 1);
    const float* C = pts + (size_t)b * NPTS * 3;

    const int widx = slots[b * NPOINT + qi];

    // q coords bit-identical to out_q (fps writes exactly P[widx])
    const float qx = C[widx * 3 + 0];
    const float qy = C[widx * 3 + 1];
    const float qz = C[widx * 3 + 2];
    const float qq = (qx * qx + qy * qy) + qz * qz;

    u64 best[KSEL];
#pragma unroll
    for (int j = 0; j < KSEL; ++j) best[j] = 0xFFFFFFFFFFFFFFFFull;

    for (int j = lane; j < NPTS; j += 64) {
      float px = C[j * 3 + 0], py = C[j * 3 + 1], pz = C[j * 3 + 2];
      float pp  = (px * px + py * py) + pz * pz;
      float dot = __builtin_fmaf(qz, pz, __builtin_fmaf(qy, py, qx * px));
      float d = (qq + pp) - 2.0f * dot;
      d = fmaxf(d, 0.0f);
      u64 key = ((u64)__float_as_uint(d) << 32) | (unsigned)j;
      if (key < best[KSEL - 1]) {
        u64 c = key;
#pragma unroll
        for (int s = 0; s < KSEL; ++s) {
          u64 o = best[s];
          bool l = c < o;
          u64 nb = l ? c : o;
          c = l ? o : c;
          best[s] = nb;
        }
      }
    }

    // LDS-free 64-way merge (validated r14/r16)
    int hp = 1;
    u64 head = best[0];
    int myK = -1, myIdx = 0;
#pragma unroll
    for (int r = 0; r < KSEL; ++r) {
      u64 v = head; int src = lane;
#pragma unroll
      for (int off = 32; off >= 1; off >>= 1) {
        u64 ov = __shfl_down(v, off);
        int os = __shfl_down(src, off);
        if (ov < v) { v = ov; src = os; }  // keys unique (idx embedded)
      }
      v   = __shfl(v, 0);
      src = __shfl(src, 0);
      if (r >= 1 && lane == r - 1) {       // drop r==0 (self)
        myIdx = (int)(unsigned)(v & 0xFFFFFFFFull);
        myK = r - 1;
      }
      if (lane == src) {
        u64 h = 0xFFFFFFFFFFFFFFFFull;
#pragma unroll
        for (int s = 1; s < KSEL; ++s) if (hp == s) h = best[s];
        head = h;
        hp++;
      }
    }

    if (myK >= 0) {
      size_t o = (size_t)(b * NPOINT + qi) * KNN + myK;
      out_nbr_mid[o] = (float)myIdx;
      float sx = C[myIdx * 3 + 0], sy = C[myIdx * 3 + 1],
            sz = C[myIdx * 3 + 2];
      out_d_mid[o * 3 + 0] = qx - sx;
      out_d_mid[o * 3 + 1] = qy - sy;
      out_d_mid[o * 3 + 2] = qz - sz;
    }
  } else {
    // ================= knn_out role: one wave per query ===================
#pragma clang fp contract(off)
    const int kb   = blockIdx.x - 512;
    const int wid  = kb * 8 + (threadIdx.x >> 6);
    const int lane = threadIdx.x & 63;
    const int b    = wid >> 10;
    const int qi   = wid & (NPOINT - 1);
    const float* C = pts + (size_t)b * NPTS * 3;

    // my query's point index
    const int wq = slots[b * NPOINT + qi];
    const float qx = C[wq * 3 + 0];
    const float qy = C[wq * 3 + 1];
    const float qz = C[wq * 3 + 2];
    const float qq = (qx * qx + qy * qy) + qz * qz;

    // candidate point indices for my 16 positions (coalesced slot reads)
    int wj[NPOINT / 64];
#pragma unroll
    for (int u = 0; u < NPOINT / 64; ++u) {
      wj[u] = slots[b * NPOINT + u * 64 + lane];
    }

    u64 best[KSEL];
#pragma unroll
    for (int j = 0; j < KSEL; ++j) best[j] = 0xFFFFFFFFFFFFFFFFull;

#pragma unroll
    for (int u = 0; u < NPOINT / 64; ++u) {
      int j = u * 64 + lane;               // candidate POSITION (the key idx)
      int w = wj[u];
      float px = C[w * 3 + 0], py = C[w * 3 + 1], pz = C[w * 3 + 2];
      float pp  = (px * px + py * py) + pz * pz;
      float dot = __builtin_fmaf(qz, pz, __builtin_fmaf(qy, py, qx * px));
      float d = (qq + pp) - 2.0f * dot;
      d = fmaxf(d, 0.0f);
      u64 key = ((u64)__float_as_uint(d) << 32) | (unsigned)j;
      if (key < best[KSEL - 1]) {
        u64 c = key;
#pragma unroll
        for (int s = 0; s < KSEL; ++s) {
          u64 o = best[s];
          bool l = c < o;
          u64 nb = l ? c : o;
          c = l ? o : c;
          best[s] = nb;
        }
      }
    }

    // LDS-free 64-way merge (validated r14/r16)
    int hp = 1;
    u64 head = best[0];
    int myK = -1, myIdx = 0;
#pragma unroll
    for (int r = 0; r < KSEL; ++r) {
      u64 v = head; int src = lane;
#pragma unroll
      for (int off = 32; off >= 1; off >>= 1) {
        u64 ov = __shfl_down(v, off);
        int os = __shfl_down(src, off);
        if (ov < v) { v = ov; src = os; }
      }
      v   = __shfl(v, 0);
      src = __shfl(src, 0);
      if (r >= 1 && lane == r - 1) {
        myIdx = (int)(unsigned)(v & 0xFFFFFFFFull);
        myK = r - 1;
      }
      if (lane == src) {
        u64 h = 0xFFFFFFFFFFFFFFFFull;
#pragma unroll
        for (int s = 1; s < KSEL; ++s) if (hp == s) h = best[s];
        head = h;
        hp++;
      }
    }

    if (myK >= 0) {
      size_t o = (size_t)(b * NPOINT + qi) * KNN + myK;
      out_nbr_out[o] = (float)myIdx;
      const int w = slots[b * NPOINT + myIdx];
      float sx = C[w * 3 + 0], sy = C[w * 3 + 1], sz = C[w * 3 + 2];
      out_d_out[o * 3 + 0] = qx - sx;
      out_d_out[o * 3 + 1] = qy - sy;
      out_d_out[o * 3 + 2] = qz - sz;
    }
  }
}

// ---------------------------------------------------------------------------
extern "C" void kernel_launch(void* const* d_in, const int* in_sizes, int n_in,
                              void* d_out, int out_size, void* d_ws,
                              size_t ws_size, hipStream_t stream) {
  (void)in_sizes; (void)n_in; (void)out_size; (void)ws_size;
  const float* pts = (const float*)d_in[0];
  float* out = (float*)d_out;

  // ws layout: int slots[4][1024] (16KB) | u64 cand[4][2][FPSB] (128B)
  int* slots = (int*)d_ws;
  u64* cand  = (u64*)((char*)d_ws + BATCH * NPOINT * sizeof(int));

  // output layout (floats): [xyz_ind | xyz_query | nbr_mid | d_mid | nbr_out | d_out]
  float* out_nbr_mid = out + (size_t)BATCH * NPOINT * 4;
  float* out_d_mid   = out_nbr_mid + (size_t)BATCH * NPOINT * KNN;
  float* out_nbr_out = out_d_mid + (size_t)BATCH * NPOINT * KNN * 3;
  float* out_d_out   = out_nbr_out + (size_t)BATCH * NPOINT * KNN;

  // Opt in to >64KB dynamic LDS (validated graph-capture-safe in r23/r24).
  static int lds_set = 0;
  if (!lds_set) {
    (void)hipFuncSetAttribute((const void*)fps_kernel,
                              hipFuncAttributeMaxDynamicSharedMemorySize,
                              DYN_LDS_BYTES);
    lds_set = 1;
  }

  hipLaunchKernelGGL(fps_kernel, dim3(2 * 8), dim3(FPST),
                     DYN_LDS_BYTES, stream, pts, out, slots, cand);
  hipLaunchKernelGGL(knn_kernel, dim3(1024), dim3(KNNT), 0, stream,
                     pts, slots, out_nbr_mid, out_d_mid, out_nbr_out,
                     out_d_out);
}